// Round 1
// baseline (583.600 us; speedup 1.0000x reference)
//
#include <hip/hip_runtime.h>
#include <hip/hip_bf16.h>
#include <math.h>

#define NB 32
#define NS 1024
#define NH 512
#define NE 1024   // 2H
#define NEGV -1e10f

// c[b][h] = b_attn[h] + sum_e hidden[b][e] * W_h[e][h]
__global__ __launch_bounds__(256) void proj_h_kernel(
    const float* __restrict__ hidden, const float* __restrict__ W_attn,
    const float* __restrict__ b_attn, float* __restrict__ c) {
  int b = blockIdx.x >> 1;
  int h = ((blockIdx.x & 1) << 8) + threadIdx.x;
  __shared__ float hid[NH];
  for (int e = threadIdx.x; e < NH; e += 256) hid[e] = hidden[b * NH + e];
  __syncthreads();
  float acc = b_attn[h];
#pragma unroll 8
  for (int e = 0; e < NH; ++e) acc = fmaf(hid[e], W_attn[(size_t)e * NH + h], acc);
  c[b * NH + h] = acc;
}

// scores[b][s] = sum_h W_v[h] * tanh(c[b][h] + sum_e enc[b][s][e]*W_e[e][h])
// Tiled fp32 GEMM: block tile 128 rows x 128 cols, BK=16, micro-tile 8x8,
// epilogue fuses tanh + W_v dot (N reduced away, proj_e never materialized).
__global__ __launch_bounds__(256) void score_kernel(
    const float* __restrict__ enc, const float* __restrict__ W_attn,
    const float* __restrict__ c, const float* __restrict__ Wv,
    float* __restrict__ scores) {
  __shared__ float As[16][132];  // [k][m], +4 pad keeps 16B align, breaks bank stride
  __shared__ float Bs[16][132];  // [k][n]
  const int tid = threadIdx.x;
  const int tx = tid & 15, ty = tid >> 4;
  const int b = blockIdx.x >> 3;
  const int s0 = (blockIdx.x & 7) << 7;
  const float* encb = enc + ((size_t)b * NS + s0) * NE;
  const float* We = W_attn + (size_t)NH * NH;  // W_e = rows 512..1535

  float sc[8];
#pragma unroll
  for (int i = 0; i < 8; ++i) sc[i] = 0.f;

  for (int nc = 0; nc < 4; ++nc) {  // 4 column chunks of 128
    float acc[8][8];
#pragma unroll
    for (int i = 0; i < 8; ++i)
#pragma unroll
      for (int j = 0; j < 8; ++j) acc[i][j] = 0.f;

    for (int kt = 0; kt < 64; ++kt) {  // K = 1024 in steps of 16
#pragma unroll
      for (int j = 0; j < 2; ++j) {
        int f4 = tid + (j << 8);
        int row = f4 >> 2, kq = (f4 & 3) << 2;
        float4 v = *(const float4*)(encb + (size_t)row * NE + (kt << 4) + kq);
        As[kq + 0][row] = v.x;
        As[kq + 1][row] = v.y;
        As[kq + 2][row] = v.z;
        As[kq + 3][row] = v.w;
        int krow = f4 >> 5, cq = (f4 & 31) << 2;
        float4 w = *(const float4*)(We + (size_t)((kt << 4) + krow) * NH + (nc << 7) + cq);
        *(float4*)&Bs[krow][cq] = w;
      }
      __syncthreads();
#pragma unroll
      for (int k = 0; k < 16; ++k) {
        float a[8], bb[8];
        *(float4*)&a[0] = *(float4*)&As[k][ty * 8];
        *(float4*)&a[4] = *(float4*)&As[k][ty * 8 + 4];
        *(float4*)&bb[0] = *(float4*)&Bs[k][tx * 8];
        *(float4*)&bb[4] = *(float4*)&Bs[k][tx * 8 + 4];
#pragma unroll
        for (int i = 0; i < 8; ++i)
#pragma unroll
          for (int j = 0; j < 8; ++j) acc[i][j] = fmaf(a[i], bb[j], acc[i][j]);
      }
      __syncthreads();
    }
    // epilogue: tanh + W_v partial dot for this 128-col chunk
    float cv[8], wv[8];
    *(float4*)&cv[0] = *(const float4*)(c + b * NH + (nc << 7) + tx * 8);
    *(float4*)&cv[4] = *(const float4*)(c + b * NH + (nc << 7) + tx * 8 + 4);
    *(float4*)&wv[0] = *(const float4*)(Wv + (nc << 7) + tx * 8);
    *(float4*)&wv[4] = *(const float4*)(Wv + (nc << 7) + tx * 8 + 4);
#pragma unroll
    for (int i = 0; i < 8; ++i) {
      float s = 0.f;
#pragma unroll
      for (int j = 0; j < 8; ++j) s += wv[j] * tanhf(acc[i][j] + cv[j]);
      sc[i] += s;
    }
  }
  // reduce partial scores across the 16 tx lanes (fixed order -> deterministic)
#pragma unroll
  for (int off = 1; off < 16; off <<= 1)
#pragma unroll
    for (int i = 0; i < 8; ++i) sc[i] += __shfl_xor(sc[i], off, 64);
  if (tx == 0) {
#pragma unroll
    for (int i = 0; i < 8; ++i) scores[b * NS + s0 + ty * 8 + i] = sc[i];
  }
}

// masked softmax over S per batch row
__global__ __launch_bounds__(256) void softmax_kernel(
    const float* __restrict__ scores, const int* __restrict__ mask,
    float* __restrict__ attn) {
  int b = blockIdx.x, tid = threadIdx.x;
  __shared__ float red[8];
  float v[4];
  float mx = -INFINITY;
#pragma unroll
  for (int j = 0; j < 4; ++j) {
    int s = tid + (j << 8);
    float x = scores[b * NS + s];
    v[j] = (mask[b * NS + s] == 0) ? NEGV : x;
    mx = fmaxf(mx, v[j]);
  }
#pragma unroll
  for (int off = 32; off >= 1; off >>= 1) mx = fmaxf(mx, __shfl_xor(mx, off, 64));
  if ((tid & 63) == 0) red[tid >> 6] = mx;
  __syncthreads();
  mx = fmaxf(fmaxf(red[0], red[1]), fmaxf(red[2], red[3]));
  float sum = 0.f;
#pragma unroll
  for (int j = 0; j < 4; ++j) {
    v[j] = __expf(v[j] - mx);
    sum += v[j];
  }
#pragma unroll
  for (int off = 32; off >= 1; off >>= 1) sum += __shfl_xor(sum, off, 64);
  __syncthreads();
  if ((tid & 63) == 0) red[4 + (tid >> 6)] = sum;
  __syncthreads();
  float inv = 1.f / (red[4] + red[5] + red[6] + red[7]);
#pragma unroll
  for (int j = 0; j < 4; ++j) attn[b * NS + tid + (j << 8)] = v[j] * inv;
}

// partial context over a 64-row S chunk: partial[b][ch][e] = sum_s w[s]*enc[b][s][e]
__global__ __launch_bounds__(256) void ctx_partial_kernel(
    const float* __restrict__ enc, const float* __restrict__ attn,
    float* __restrict__ partial) {
  int ch = blockIdx.x;  // 0..15
  int b = blockIdx.y;
  int tid = threadIdx.x;
  __shared__ float w[64];
  if (tid < 64) w[tid] = attn[b * NS + (ch << 6) + tid];
  __syncthreads();
  const float* encb = enc + ((size_t)b * NS + (ch << 6)) * NE;
  float4 acc = make_float4(0.f, 0.f, 0.f, 0.f);
  int e = tid << 2;
  for (int s = 0; s < 64; ++s) {
    float4 x = *(const float4*)(encb + (size_t)s * NE + e);
    float ws_ = w[s];
    acc.x = fmaf(ws_, x.x, acc.x);
    acc.y = fmaf(ws_, x.y, acc.y);
    acc.z = fmaf(ws_, x.z, acc.z);
    acc.w = fmaf(ws_, x.w, acc.w);
  }
  *(float4*)(partial + ((size_t)(b * 16 + ch)) * NE + e) = acc;
}

__global__ __launch_bounds__(256) void ctx_reduce_kernel(
    const float* __restrict__ partial, float* __restrict__ ctx) {
  int b = blockIdx.x;
  int e = threadIdx.x << 2;
  float4 acc = make_float4(0.f, 0.f, 0.f, 0.f);
  for (int ch = 0; ch < 16; ++ch) {
    float4 x = *(const float4*)(partial + ((size_t)(b * 16 + ch)) * NE + e);
    acc.x += x.x;
    acc.y += x.y;
    acc.z += x.z;
    acc.w += x.w;
  }
  *(float4*)(ctx + (size_t)b * NE + e) = acc;
}

extern "C" void kernel_launch(void* const* d_in, const int* in_sizes, int n_in,
                              void* d_out, int out_size, void* d_ws, size_t ws_size,
                              hipStream_t stream) {
  const float* hidden = (const float*)d_in[0];
  const float* enc = (const float*)d_in[1];
  const int* mask = (const int*)d_in[2];
  const float* W_attn = (const float*)d_in[3];
  const float* b_attn = (const float*)d_in[4];
  const float* W_v = (const float*)d_in[5];

  float* ctx = (float*)d_out;             // context: 32*1024
  float* attn = ctx + NB * NS;            // attn_w: 32*1024

  float* ws = (float*)d_ws;
  float* c = ws;                          // 32*512
  float* scores = ws + NB * NH;           // 32*1024
  float* partial = ws + NB * NH + NB * NS;  // 32*16*1024

  proj_h_kernel<<<64, 256, 0, stream>>>(hidden, W_attn, b_attn, c);
  score_kernel<<<256, 256, 0, stream>>>(enc, W_attn, c, W_v, scores);
  softmax_kernel<<<32, 256, 0, stream>>>(scores, mask, attn);
  ctx_partial_kernel<<<dim3(16, NB), 256, 0, stream>>>(enc, attn, partial);
  ctx_reduce_kernel<<<32, 256, 0, stream>>>(partial, ctx);
}

// Round 2
// 163.014 us; speedup vs baseline: 3.5801x; 3.5801x over previous
//
#include <hip/hip_runtime.h>
#include <hip/hip_bf16.h>
#include <math.h>

#define NB 32
#define NS 1024
#define NH 512
#define NE 1024   // 2H
#define NEGV -1e10f

typedef _Float16 f16x8 __attribute__((ext_vector_type(8)));
typedef _Float16 f16x4 __attribute__((ext_vector_type(4)));
typedef float f32x4 __attribute__((ext_vector_type(4)));

// c[b][h] = b_attn[h] + sum_e hidden[b][e] * W_h[e][h]   (fp32, tiny)
__global__ __launch_bounds__(256) void proj_h_kernel(
    const float* __restrict__ hidden, const float* __restrict__ W_attn,
    const float* __restrict__ b_attn, float* __restrict__ c) {
  int b = blockIdx.x >> 1;
  int h = ((blockIdx.x & 1) << 8) + threadIdx.x;
  __shared__ float hid[NH];
  for (int e = threadIdx.x; e < NH; e += 256) hid[e] = hidden[b * NH + e];
  __syncthreads();
  float acc = b_attn[h];
#pragma unroll 8
  for (int e = 0; e < NH; ++e) acc = fmaf(hid[e], W_attn[(size_t)e * NH + h], acc);
  c[b * NH + h] = acc;
}

// WeT[col][k] = fp16(W_e[k][col]) — transposed so MFMA B-frags (8 consecutive k
// per lane at fixed col) are contiguous 16B global loads.
__global__ __launch_bounds__(256) void prep_We_kernel(
    const float* __restrict__ W_attn, _Float16* __restrict__ WeT) {
  int k = blockIdx.x;  // 0..1023
  const float* src = W_attn + (size_t)(NH + k) * NH;
#pragma unroll
  for (int j = 0; j < 2; ++j) {
    int col = threadIdx.x + (j << 8);
    WeT[(size_t)col * NE + k] = (_Float16)src[col];
  }
}

// scores partial: fused  tanh(enc@W_e + c) . W_v  over a 128-col chunk.
// fp16 MFMA 16x16x32, tile 128x128, BK=64, 4 waves (2x2 of 64x64).
__global__ __launch_bounds__(256) void score_kernel(
    const float* __restrict__ enc, const _Float16* __restrict__ WeT,
    const float* __restrict__ c, const float* __restrict__ Wv,
    float* __restrict__ spart) {
  __shared__ _Float16 Asm[128 * 64];  // [row][k] fp16, row stride 128B, XOR-swizzled
  const int tid = threadIdx.x;
  const int lane = tid & 63;
  const int wid = tid >> 6;
  const int wr = wid >> 1, wc = wid & 1;
  const int b = blockIdx.x >> 3;
  const int s0 = (blockIdx.x & 7) << 7;
  const int nc = blockIdx.y;  // 0..3 column chunk of 128
  const int colbase = (nc << 7) + (wc << 6);
  const float* encb = enc + ((size_t)b * NS + s0) * NE;

  f32x4 acc[4][4];
#pragma unroll
  for (int i = 0; i < 4; ++i)
#pragma unroll
    for (int j = 0; j < 4; ++j) acc[i][j] = (f32x4)0.f;

  for (int kt = 0; kt < 16; ++kt) {  // K = 1024, BK = 64
    // ---- stage A: 128x64 fp32 -> fp16, swizzled LDS ----
#pragma unroll
    for (int q = 0; q < 8; ++q) {
      int f4 = (q << 8) + tid;
      int row = f4 >> 4;       // 0..127
      int kq = f4 & 15;        // float4 index within the 64-float row
      float4 v = *(const float4*)(encb + (size_t)row * NE + (kt << 6) + (kq << 2));
      f16x4 h;
      h[0] = (_Float16)v.x; h[1] = (_Float16)v.y;
      h[2] = (_Float16)v.z; h[3] = (_Float16)v.w;
      int off = (row << 7) + (kq << 3);
      off ^= (row & 7) << 4;   // bank-conflict swizzle (G4)
      *(f16x4*)((char*)Asm + off) = h;
    }
    __syncthreads();
    // ---- compute: 2 k-slices of 32 ----
#pragma unroll
    for (int kk = 0; kk < 2; ++kk) {
      f16x8 af[4], bf[4];
#pragma unroll
      for (int i = 0; i < 4; ++i) {
        int row = (wr << 6) + (i << 4) + (lane & 15);
        int off = (row << 7) + (kk << 6) + ((lane >> 4) << 4);
        off ^= (row & 7) << 4;
        af[i] = *(const f16x8*)((const char*)Asm + off);
      }
#pragma unroll
      for (int j = 0; j < 4; ++j) {
        int col = colbase + (j << 4) + (lane & 15);
        bf[j] = *(const f16x8*)(WeT + (size_t)col * NE + (kt << 6) + (kk << 5) +
                                ((lane >> 4) << 3));
      }
#pragma unroll
      for (int i = 0; i < 4; ++i)
#pragma unroll
        for (int j = 0; j < 4; ++j)
          acc[i][j] = __builtin_amdgcn_mfma_f32_16x16x32_f16(af[i], bf[j], acc[i][j], 0, 0, 0);
    }
    __syncthreads();
  }

  // ---- epilogue: tanh + W_v dot over this wave's 64 cols ----
  float sr[4][4];  // [mi][reg]
#pragma unroll
  for (int i = 0; i < 4; ++i)
#pragma unroll
    for (int r = 0; r < 4; ++r) sr[i][r] = 0.f;
  int cb = lane & 15;
#pragma unroll
  for (int j = 0; j < 4; ++j) {
    int hcol = colbase + (j << 4) + cb;
    float wvj = Wv[hcol];
    float cvj = c[b * NH + hcol];
#pragma unroll
    for (int i = 0; i < 4; ++i)
#pragma unroll
      for (int r = 0; r < 4; ++r)
        sr[i][r] += wvj * tanhf(acc[i][j][r] + cvj);
  }
  // reduce across the 16 cols held by lanes (lane&15 groups)
#pragma unroll
  for (int off = 1; off < 16; off <<= 1)
#pragma unroll
    for (int i = 0; i < 4; ++i)
#pragma unroll
      for (int r = 0; r < 4; ++r) sr[i][r] += __shfl_xor(sr[i][r], off, 64);
  if ((lane & 15) == 0) {
    float* dst = spart + (size_t)((nc << 1) + wc) * NB * NS + b * NS + s0;
#pragma unroll
    for (int i = 0; i < 4; ++i)
#pragma unroll
      for (int r = 0; r < 4; ++r)
        dst[(wr << 6) + (i << 4) + ((lane >> 4) << 2) + r] = sr[i][r];
  }
}

// masked softmax over S per batch row; sums the 8 score partials first
__global__ __launch_bounds__(256) void softmax_kernel(
    const float* __restrict__ spart, const int* __restrict__ mask,
    float* __restrict__ attn) {
  int b = blockIdx.x, tid = threadIdx.x;
  __shared__ float red[8];
  float v[4];
  float mx = -INFINITY;
#pragma unroll
  for (int j = 0; j < 4; ++j) {
    int s = tid + (j << 8);
    float x = 0.f;
#pragma unroll
    for (int p = 0; p < 8; ++p) x += spart[(size_t)p * NB * NS + b * NS + s];
    v[j] = (mask[b * NS + s] == 0) ? NEGV : x;
    mx = fmaxf(mx, v[j]);
  }
#pragma unroll
  for (int off = 32; off >= 1; off >>= 1) mx = fmaxf(mx, __shfl_xor(mx, off, 64));
  if ((tid & 63) == 0) red[tid >> 6] = mx;
  __syncthreads();
  mx = fmaxf(fmaxf(red[0], red[1]), fmaxf(red[2], red[3]));
  float sum = 0.f;
#pragma unroll
  for (int j = 0; j < 4; ++j) {
    v[j] = __expf(v[j] - mx);
    sum += v[j];
  }
#pragma unroll
  for (int off = 32; off >= 1; off >>= 1) sum += __shfl_xor(sum, off, 64);
  __syncthreads();
  if ((tid & 63) == 0) red[4 + (tid >> 6)] = sum;
  __syncthreads();
  float inv = 1.f / (red[4] + red[5] + red[6] + red[7]);
#pragma unroll
  for (int j = 0; j < 4; ++j) attn[b * NS + tid + (j << 8)] = v[j] * inv;
}

// partial context over a 64-row S chunk
__global__ __launch_bounds__(256) void ctx_partial_kernel(
    const float* __restrict__ enc, const float* __restrict__ attn,
    float* __restrict__ partial) {
  int ch = blockIdx.x;  // 0..15
  int b = blockIdx.y;
  int tid = threadIdx.x;
  __shared__ float w[64];
  if (tid < 64) w[tid] = attn[b * NS + (ch << 6) + tid];
  __syncthreads();
  const float* encb = enc + ((size_t)b * NS + (ch << 6)) * NE;
  float4 acc = make_float4(0.f, 0.f, 0.f, 0.f);
  int e = tid << 2;
  for (int s = 0; s < 64; ++s) {
    float4 x = *(const float4*)(encb + (size_t)s * NE + e);
    float ws_ = w[s];
    acc.x = fmaf(ws_, x.x, acc.x);
    acc.y = fmaf(ws_, x.y, acc.y);
    acc.z = fmaf(ws_, x.z, acc.z);
    acc.w = fmaf(ws_, x.w, acc.w);
  }
  *(float4*)(partial + ((size_t)(b * 16 + ch)) * NE + e) = acc;
}

__global__ __launch_bounds__(256) void ctx_reduce_kernel(
    const float* __restrict__ partial, float* __restrict__ ctx) {
  int b = blockIdx.x;
  int e = threadIdx.x << 2;
  float4 acc = make_float4(0.f, 0.f, 0.f, 0.f);
  for (int ch = 0; ch < 16; ++ch) {
    float4 x = *(const float4*)(partial + ((size_t)(b * 16 + ch)) * NE + e);
    acc.x += x.x;
    acc.y += x.y;
    acc.z += x.z;
    acc.w += x.w;
  }
  *(float4*)(ctx + (size_t)b * NE + e) = acc;
}

extern "C" void kernel_launch(void* const* d_in, const int* in_sizes, int n_in,
                              void* d_out, int out_size, void* d_ws, size_t ws_size,
                              hipStream_t stream) {
  const float* hidden = (const float*)d_in[0];
  const float* enc = (const float*)d_in[1];
  const int* mask = (const int*)d_in[2];
  const float* W_attn = (const float*)d_in[3];
  const float* b_attn = (const float*)d_in[4];
  const float* W_v = (const float*)d_in[5];

  float* ctx = (float*)d_out;   // context: 32*1024
  float* attn = ctx + NB * NS;  // attn_w: 32*1024

  float* ws = (float*)d_ws;
  float* c = ws;                                       // 32*512 f32
  _Float16* WeT = (_Float16*)(ws + NB * NH);           // 512*1024 fp16 (1 MB)
  float* spart = (float*)((char*)WeT + (size_t)NH * NE * 2);  // 8*32*1024 f32
  float* partial = spart + 8 * NB * NS;                // 32*16*1024 f32

  proj_h_kernel<<<64, 256, 0, stream>>>(hidden, W_attn, b_attn, c);
  prep_We_kernel<<<NE, 256, 0, stream>>>(W_attn, WeT);
  score_kernel<<<dim3(256, 4), 256, 0, stream>>>(enc, WeT, c, W_v, spart);
  softmax_kernel<<<NB, 256, 0, stream>>>(spart, mask, attn);
  ctx_partial_kernel<<<dim3(16, NB), 256, 0, stream>>>(enc, attn, partial);
  ctx_reduce_kernel<<<NB, 256, 0, stream>>>(partial, ctx);
}

// Round 3
// 128.930 us; speedup vs baseline: 4.5265x; 1.2644x over previous
//
#include <hip/hip_runtime.h>
#include <hip/hip_bf16.h>
#include <math.h>

#define NB 32
#define NS 1024
#define NH 512
#define NE 1024   // 2H
#define NEGV -1e10f

typedef _Float16 f16x8 __attribute__((ext_vector_type(8)));
typedef _Float16 f16x4 __attribute__((ext_vector_type(4)));
typedef float f32x4 __attribute__((ext_vector_type(4)));

// c[b][h] = b_attn[h] + sum_e hidden[b][e] * W_h[e][h]   (fp32, tiny)
__global__ __launch_bounds__(256) void proj_h_kernel(
    const float* __restrict__ hidden, const float* __restrict__ W_attn,
    const float* __restrict__ b_attn, float* __restrict__ c) {
  int b = blockIdx.x >> 1;
  int h = ((blockIdx.x & 1) << 8) + threadIdx.x;
  __shared__ float hid[NH];
  for (int e = threadIdx.x; e < NH; e += 256) hid[e] = hidden[b * NH + e];
  __syncthreads();
  float acc = b_attn[h];
#pragma unroll 8
  for (int e = 0; e < NH; ++e) acc = fmaf(hid[e], W_attn[(size_t)e * NH + h], acc);
  c[b * NH + h] = acc;
}

// WeT[col][k] = fp16(W_e[k][col]) — transposed so B k-runs are contiguous.
__global__ __launch_bounds__(256) void prep_We_kernel(
    const float* __restrict__ W_attn, _Float16* __restrict__ WeT) {
  int k = blockIdx.x;  // 0..1023
  const float* src = W_attn + (size_t)(NH + k) * NH;
#pragma unroll
  for (int j = 0; j < 2; ++j) {
    int col = threadIdx.x + (j << 8);
    WeT[(size_t)col * NE + k] = (_Float16)src[col];
  }
}

// Fused  tanh(enc@W_e + c) . W_v  partials over a 256-col chunk.
// m97 structure: tile 64(M)x256(N), BK=64, 4 waves (wave tile 64x64, acc 4x4).
// A: reg-staged fp32->fp16 swizzled LDS. B: global_load_lds w/ pre-swizzled src.
__global__ __launch_bounds__(256) void score_kernel(
    const float* __restrict__ enc, const _Float16* __restrict__ WeT,
    const float* __restrict__ c, const float* __restrict__ Wv,
    float* __restrict__ spart) {
  __shared__ _Float16 Asm[64 * 64];    // [row][k] swizzled, 8 KB
  __shared__ _Float16 Bsm[256 * 64];   // [col][k] swizzled, 32 KB
  const int tid = threadIdx.x;
  const int lane = tid & 63;
  const int wid = tid >> 6;  // wave = N-position (4 waves across 256 cols)
  const int bx = blockIdx.x;                 // 512 M-tiles
  const int lb = ((bx & 7) << 6) + (bx >> 3);  // bijective XCD swizzle (512%8==0)
  const int b = lb >> 4;
  const int s0 = (lb & 15) << 6;
  const int nc = blockIdx.y;  // 0..1 column chunk of 256
  const float* encb = enc + ((size_t)b * NS + s0) * NE;
  const char* Wbytes = (const char*)(WeT + ((size_t)(nc << 8)) * NE);

  f32x4 acc[4][4];
#pragma unroll
  for (int i = 0; i < 4; ++i)
#pragma unroll
    for (int j = 0; j < 4; ++j) acc[i][j] = (f32x4)0.f;

  for (int kt = 0; kt < 16; ++kt) {  // K = 1024, BK = 64
    // ---- stage A: 64x64 fp32 -> fp16, swizzled (G4) ----
#pragma unroll
    for (int q = 0; q < 4; ++q) {
      int f4 = (q << 8) + tid;
      int row = f4 >> 4, kq = f4 & 15;
      float4 v = *(const float4*)(encb + (size_t)row * NE + (kt << 6) + (kq << 2));
      f16x4 h;
      h[0] = (_Float16)v.x; h[1] = (_Float16)v.y;
      h[2] = (_Float16)v.z; h[3] = (_Float16)v.w;
      int off = (row << 7) + (kq << 3);
      off ^= (row & 7) << 4;
      *(f16x4*)((char*)Asm + off) = h;
    }
    // ---- stage B: 256x64 fp16 via global_load_lds, pre-swizzled source ----
    // LDS[d]: col=d>>7, kbyte=(d&127)^((col&7)<<4)  (rule #21: linear dest,
    // inverse-swizzled src, swizzled read)
    {
      const char* Wkt = Wbytes + ((size_t)kt << 7);
#pragma unroll
      for (int i = 0; i < 8; ++i) {
        int dbase = (wid << 13) + (i << 10);      // wave-uniform dest base
        int d = dbase + (lane << 4);              // this lane's dest byte
        int col = d >> 7;
        int sbyte = (d & 127) ^ ((col & 7) << 4);
        const char* src = Wkt + (size_t)col * (NE * 2) + sbyte;
        __builtin_amdgcn_global_load_lds(
            (const __attribute__((address_space(1))) uint32_t*)src,
            (__attribute__((address_space(3))) uint32_t*)((char*)Bsm + dbase),
            16, 0, 0);
      }
    }
    __syncthreads();
    // ---- compute: 2 k-slices of 32 ----
#pragma unroll
    for (int kk = 0; kk < 2; ++kk) {
      f16x8 af[4], bf[4];
#pragma unroll
      for (int mi = 0; mi < 4; ++mi) {
        int row = (mi << 4) + (lane & 15);
        int off = (row << 7) + (kk << 6) + ((lane >> 4) << 4);
        off ^= (row & 7) << 4;
        af[mi] = *(const f16x8*)((const char*)Asm + off);
      }
#pragma unroll
      for (int nj = 0; nj < 4; ++nj) {
        int cb = (wid << 6) + (nj << 4) + (lane & 15);
        int off = (cb << 7) + (kk << 6) + ((lane >> 4) << 4);
        off ^= (cb & 7) << 4;
        bf[nj] = *(const f16x8*)((const char*)Bsm + off);
      }
#pragma unroll
      for (int mi = 0; mi < 4; ++mi)
#pragma unroll
        for (int nj = 0; nj < 4; ++nj)
          acc[mi][nj] = __builtin_amdgcn_mfma_f32_16x16x32_f16(af[mi], bf[nj], acc[mi][nj], 0, 0, 0);
    }
    __syncthreads();
  }

  // ---- epilogue: tanh + W_v dot over this wave's 64 cols ----
  float sr[4][4];
#pragma unroll
  for (int i = 0; i < 4; ++i)
#pragma unroll
    for (int r = 0; r < 4; ++r) sr[i][r] = 0.f;
#pragma unroll
  for (int nj = 0; nj < 4; ++nj) {
    int hcol = (nc << 8) + (wid << 6) + (nj << 4) + (lane & 15);
    float wvj = Wv[hcol];
    float cvj = c[b * NH + hcol];
#pragma unroll
    for (int mi = 0; mi < 4; ++mi)
#pragma unroll
      for (int r = 0; r < 4; ++r)
        sr[mi][r] += wvj * tanhf(acc[mi][nj][r] + cvj);
  }
  // reduce across the 16 col-lanes (fixed order -> deterministic)
#pragma unroll
  for (int off = 1; off < 16; off <<= 1)
#pragma unroll
    for (int mi = 0; mi < 4; ++mi)
#pragma unroll
      for (int r = 0; r < 4; ++r) sr[mi][r] += __shfl_xor(sr[mi][r], off, 64);
  if ((lane & 15) == 0) {
    float* dst = spart + (size_t)((nc << 2) + wid) * NB * NS + b * NS + s0;
#pragma unroll
    for (int mi = 0; mi < 4; ++mi)
#pragma unroll
      for (int r = 0; r < 4; ++r)
        dst[(mi << 4) + ((lane >> 4) << 2) + r] = sr[mi][r];
  }
}

// masked softmax over S per batch row; sums the 8 score partials first
__global__ __launch_bounds__(256) void softmax_kernel(
    const float* __restrict__ spart, const int* __restrict__ mask,
    float* __restrict__ attn) {
  int b = blockIdx.x, tid = threadIdx.x;
  __shared__ float red[8];
  float v[4];
  float mx = -INFINITY;
#pragma unroll
  for (int j = 0; j < 4; ++j) {
    int s = tid + (j << 8);
    float x = 0.f;
#pragma unroll
    for (int p = 0; p < 8; ++p) x += spart[(size_t)p * NB * NS + b * NS + s];
    v[j] = (mask[b * NS + s] == 0) ? NEGV : x;
    mx = fmaxf(mx, v[j]);
  }
#pragma unroll
  for (int off = 32; off >= 1; off >>= 1) mx = fmaxf(mx, __shfl_xor(mx, off, 64));
  if ((tid & 63) == 0) red[tid >> 6] = mx;
  __syncthreads();
  mx = fmaxf(fmaxf(red[0], red[1]), fmaxf(red[2], red[3]));
  float sum = 0.f;
#pragma unroll
  for (int j = 0; j < 4; ++j) {
    v[j] = __expf(v[j] - mx);
    sum += v[j];
  }
#pragma unroll
  for (int off = 32; off >= 1; off >>= 1) sum += __shfl_xor(sum, off, 64);
  __syncthreads();
  if ((tid & 63) == 0) red[4 + (tid >> 6)] = sum;
  __syncthreads();
  float inv = 1.f / (red[4] + red[5] + red[6] + red[7]);
#pragma unroll
  for (int j = 0; j < 4; ++j) attn[b * NS + tid + (j << 8)] = v[j] * inv;
}

// partial context over a 64-row S chunk
__global__ __launch_bounds__(256) void ctx_partial_kernel(
    const float* __restrict__ enc, const float* __restrict__ attn,
    float* __restrict__ partial) {
  int ch = blockIdx.x;  // 0..15
  int b = blockIdx.y;
  int tid = threadIdx.x;
  __shared__ float w[64];
  if (tid < 64) w[tid] = attn[b * NS + (ch << 6) + tid];
  __syncthreads();
  const float* encb = enc + ((size_t)b * NS + (ch << 6)) * NE;
  float4 acc = make_float4(0.f, 0.f, 0.f, 0.f);
  int e = tid << 2;
  for (int s = 0; s < 64; ++s) {
    float4 x = *(const float4*)(encb + (size_t)s * NE + e);
    float ws_ = w[s];
    acc.x = fmaf(ws_, x.x, acc.x);
    acc.y = fmaf(ws_, x.y, acc.y);
    acc.z = fmaf(ws_, x.z, acc.z);
    acc.w = fmaf(ws_, x.w, acc.w);
  }
  *(float4*)(partial + ((size_t)(b * 16 + ch)) * NE + e) = acc;
}

__global__ __launch_bounds__(256) void ctx_reduce_kernel(
    const float* __restrict__ partial, float* __restrict__ ctx) {
  int b = blockIdx.x;
  int e = threadIdx.x << 2;
  float4 acc = make_float4(0.f, 0.f, 0.f, 0.f);
  for (int ch = 0; ch < 16; ++ch) {
    float4 x = *(const float4*)(partial + ((size_t)(b * 16 + ch)) * NE + e);
    acc.x += x.x;
    acc.y += x.y;
    acc.z += x.z;
    acc.w += x.w;
  }
  *(float4*)(ctx + (size_t)b * NE + e) = acc;
}

extern "C" void kernel_launch(void* const* d_in, const int* in_sizes, int n_in,
                              void* d_out, int out_size, void* d_ws, size_t ws_size,
                              hipStream_t stream) {
  const float* hidden = (const float*)d_in[0];
  const float* enc = (const float*)d_in[1];
  const int* mask = (const int*)d_in[2];
  const float* W_attn = (const float*)d_in[3];
  const float* b_attn = (const float*)d_in[4];
  const float* W_v = (const float*)d_in[5];

  float* ctx = (float*)d_out;   // context: 32*1024
  float* attn = ctx + NB * NS;  // attn_w: 32*1024

  float* ws = (float*)d_ws;
  float* c = ws;                                       // 32*512 f32
  _Float16* WeT = (_Float16*)(ws + NB * NH);           // 512*1024 fp16 (1 MB)
  float* spart = (float*)((char*)WeT + (size_t)NH * NE * 2);  // 8*32*1024 f32
  float* partial = spart + 8 * NB * NS;                // 32*16*1024 f32

  proj_h_kernel<<<64, 256, 0, stream>>>(hidden, W_attn, b_attn, c);
  prep_We_kernel<<<NE, 256, 0, stream>>>(W_attn, WeT);
  score_kernel<<<dim3(512, 2), 256, 0, stream>>>(enc, WeT, c, W_v, spart);
  softmax_kernel<<<NB, 256, 0, stream>>>(spart, mask, attn);
  ctx_partial_kernel<<<dim3(16, NB), 256, 0, stream>>>(enc, attn, partial);
  ctx_reduce_kernel<<<NB, 256, 0, stream>>>(partial, ctx);
}